// Round 22
// baseline (176.218 us; speedup 1.0000x reference)
//
#include <hip/hip_runtime.h>

#define NSLOPE  0.2f
#define LEXP(v) __expf((v) >= 0.f ? (v) : NSLOPE * (v))

typedef __attribute__((ext_vector_type(8))) short bf16x8;
typedef __attribute__((ext_vector_type(4))) float f32x4;

__device__ __forceinline__ unsigned bf16_rne(float f) {
    unsigned x = __float_as_uint(f);
    return (x + 0x7fffu + ((x >> 16) & 1u)) >> 16;
}
__device__ __forceinline__ float bf_lo(unsigned u) { return __uint_as_float(u << 16); }
__device__ __forceinline__ float bf_hi(unsigned u) { return __uint_as_float(u & 0xffff0000u); }

// ---- Kernel 1: blocks [0,512): h2 = bf16(x@W^T) via MFMA + att dots via
// 4 extra MFMAs against watt = att@W. Block 512: init gcur[b] = b*CAP.
__global__ __launch_bounds__(256) void k_gemm_init(
    const float* __restrict__ x, const float* __restrict__ Wg,
    const float* __restrict__ att_src, const float* __restrict__ att_dst,
    unsigned* __restrict__ h2, float* __restrict__ a_src, float* __restrict__ a_dst,
    int N, int* __restrict__ gcur, int nbkt, int cap)
{
    __shared__ unsigned short Wl[128 * 136];   // bf16 W (34.8KB)
    __shared__ unsigned short wattH[8][128];   // bf16 watt (2KB)

    const int t = threadIdx.x;

    if (blockIdx.x >= 512) {                   // ---- gcur init role ----
        for (int i = t; i < nbkt; i += 256) gcur[i] = i * cap;
        return;
    }

    // ---- GEMM role ----
    for (int i = t; i < 128 * 32; i += 256) {
        int r = i >> 5, c4 = (i & 31) * 4;
        float4 w = *(const float4*)(Wg + r * 128 + c4);
        unsigned* wp = (unsigned*)((char*)Wl + r * 272 + c4 * 2);
        wp[0] = bf16_rne(w.x) | (bf16_rne(w.y) << 16);
        wp[1] = bf16_rne(w.z) | (bf16_rne(w.w) << 16);
    }
    // watt[j][f]: j<4 -> src head j; j>=4 -> dst head j-4
    for (int idx = t; idx < 1024; idx += 256) {
        int j = idx >> 7, f = idx & 127;
        const float* av = (j < 4) ? (att_src + j * 32) : (att_dst + (j - 4) * 32);
        int hh = (j & 3) * 32;
        float s = 0.f;
        #pragma unroll 8
        for (int k = 0; k < 32; ++k)
            s += av[k] * Wg[(size_t)(hh + k) * 128 + f];
        wattH[j][f] = (unsigned short)bf16_rne(s);
    }
    __syncthreads();

    const int wave = t >> 6, l = t & 63;
    const int col = l & 15, kg = l >> 4;

    union { bf16x8 v; unsigned short s[8]; } batt[4];
    #pragma unroll
    for (int s4 = 0; s4 < 4; ++s4) {
        #pragma unroll
        for (int jj = 0; jj < 8; ++jj)
            batt[s4].s[jj] = (col < 8) ? wattH[col][s4 * 32 + kg * 8 + jj]
                                       : (unsigned short)0;
    }

    const int nwaves = 512 * 4;
    const int wid = blockIdx.x * 4 + wave;

    for (int mb = wid * 16; mb < N; mb += nwaves * 16) {
        union { bf16x8 v; unsigned u[4]; } af[4];
        int row = mb + col; if (row >= N) row = N - 1;
        const float* xr = x + (size_t)row * 128 + kg * 8;
        #pragma unroll
        for (int s = 0; s < 4; ++s) {
            float4 xa = *(const float4*)(xr + s * 32);
            float4 xb = *(const float4*)(xr + s * 32 + 4);
            af[s].u[0] = bf16_rne(xa.x) | (bf16_rne(xa.y) << 16);
            af[s].u[1] = bf16_rne(xa.z) | (bf16_rne(xa.w) << 16);
            af[s].u[2] = bf16_rne(xb.x) | (bf16_rne(xb.y) << 16);
            af[s].u[3] = bf16_rne(xb.z) | (bf16_rne(xb.w) << 16);
        }

        f32x4 acc[8];
        #pragma unroll
        for (int tl = 0; tl < 8; ++tl) acc[tl] = (f32x4){0.f, 0.f, 0.f, 0.f};
        f32x4 accd = (f32x4){0.f, 0.f, 0.f, 0.f};

        #pragma unroll
        for (int s = 0; s < 4; ++s) {
            #pragma unroll
            for (int tl = 0; tl < 8; ++tl) {
                const bf16x8 bf = *(const bf16x8*)((char*)Wl
                    + (tl * 16 + col) * 272 + (s * 32 + kg * 8) * 2);
                acc[tl] = __builtin_amdgcn_mfma_f32_16x16x32_bf16(af[s].v, bf, acc[tl], 0, 0, 0);
            }
            accd = __builtin_amdgcn_mfma_f32_16x16x32_bf16(af[s].v, batt[s].v, accd, 0, 0, 0);
        }

        #pragma unroll
        for (int tl = 0; tl < 4; ++tl) {
            #pragma unroll
            for (int r = 0; r < 4; ++r) {
                int node = mb + kg * 4 + r;
                if (node < N) {
                    unsigned w = bf16_rne(acc[tl][r]) | (bf16_rne(acc[tl + 4][r]) << 16);
                    h2[(size_t)node * 64 + tl * 16 + col] = w;
                }
            }
        }
        if (col < 8) {
            float* bp = (col < 4) ? a_src : a_dst;
            const int j = col & 3;
            #pragma unroll
            for (int r = 0; r < 4; ++r) {
                int node = mb + kg * 4 + r;
                if (node < N) bp[(size_t)node * 4 + j] = accd[r];
            }
        }
    }
}

// ---- Kernel 2: fused count + reserve + scatter into padded bucket regions.
// Buckets of 64 nodes: bucket = d>>6, dlow = d&63 packed at bit 26.
__global__ __launch_bounds__(256) void k_partB2(
    const int* __restrict__ ei, int* __restrict__ gcur,
    unsigned* __restrict__ stage, int E, int nbkt, int chunk)
{
    __shared__ int dstc[6272];
    __shared__ int lcnt[1600];
    __shared__ int lbase[1600];
    const int t = threadIdx.x;
    for (int i = t; i < nbkt; i += 256) lcnt[i] = 0;
    __syncthreads();
    const int lo = blockIdx.x * chunk, hi = min(lo + chunk, E);
    for (int e = lo + t; e < hi; e += 256) {
        int d = ei[E + e];
        dstc[e - lo] = d;
        atomicAdd(&lcnt[d >> 6], 1);
    }
    __syncthreads();
    for (int i = t; i < nbkt; i += 256) {
        int c = lcnt[i];
        lbase[i] = (c > 0) ? atomicAdd(&gcur[i], c) : 0;
    }
    __syncthreads();
    for (int e = lo + t; e < hi; e += 256) {
        int s = ei[e];
        int d = dstc[e - lo];
        int pos = atomicAdd(&lbase[d >> 6], 1);
        stage[pos] = (unsigned)s | ((unsigned)(d & 63) << 26);
    }
}

// ---- Kernel 3 (fused partC + agg), 512 threads / 8 waves per block.
// Build: count, scan, scatter edges into LDS (bf16 exps), pad to mult-of-8.
// Agg: full-row uint4 gathers (16 lanes/row, 4 edges/slot) — a 6-slot batch
// covers 24 edges, >= typical padded run, so most nodes issue their whole
// edge list in one burst. Slot validity (4k < rem) is wave-uniform.
__global__ __launch_bounds__(512) void k_aggC(
    const unsigned* __restrict__ stage, const int* __restrict__ gcur,
    const float* __restrict__ a_src, const float* __restrict__ a_dst,
    const unsigned* __restrict__ h2, const float* __restrict__ b_gat,
    const float* __restrict__ W_lin, const float* __restrict__ b_lin,
    float* __restrict__ out, int N, int cap)
{
    __shared__ int      eS[1728];
    __shared__ unsigned eA0[1728];
    __shared__ unsigned eA1[1728];
    __shared__ int cnt[64];
    __shared__ int cur[64];
    __shared__ int rs[64];
    __shared__ int re[64];
    __shared__ float adl[64][4];

    const int b = blockIdx.x, t = threadIdx.x;
    const int wave = t >> 6, l = t & 63;

    if (t < 64) {
        cnt[t] = 0;
        int n = (b << 6) + t;
        float4 v = (n < N) ? *(const float4*)(a_dst + (size_t)n * 4)
                           : make_float4(0.f, 0.f, 0.f, 0.f);
        *(float4*)adl[t] = v;
    }
    __syncthreads();
    const int slo = b * cap;
    const int ecnt = gcur[b] - slo;
    for (int e = t; e < ecnt; e += 512)
        atomicAdd(&cnt[stage[slo + e] >> 26], 1);
    __syncthreads();
    if (t < 64) {                   // single-wave scan (wave 0)
        int v = cnt[t];
        int pv = (v + 7) & ~7;      // padded run length
        int sc = pv;
        #pragma unroll
        for (int m = 1; m < 64; m <<= 1) {
            int u = __shfl_up(sc, m);
            if (t >= m) sc += u;
        }
        int c0 = sc - pv;           // LDS-local offset
        cur[t] = c0;
        rs[t] = c0; re[t] = c0 + pv;
    }
    __syncthreads();
    for (int e = t; e < ecnt; e += 512) {
        unsigned u = stage[slo + e];
        int s  = (int)(u & 0x3FFFFFFu);
        int dl = (int)(u >> 26);
        float4 av = *(const float4*)(a_src + (size_t)s * 4);
        float x0 = LEXP(av.x + adl[dl][0]);
        float x1 = LEXP(av.y + adl[dl][1]);
        float x2 = LEXP(av.z + adl[dl][2]);
        float x3 = LEXP(av.w + adl[dl][3]);
        int pos = atomicAdd(&cur[dl], 1);
        eS[pos]  = s;
        eA0[pos] = bf16_rne(x0) | (bf16_rne(x2) << 16);
        eA1[pos] = bf16_rne(x1) | (bf16_rne(x3) << 16);
    }
    __syncthreads();
    if (t < 64) {
        int n = (b << 6) + t;
        if (n < N) {
            const int e1 = cur[t], pe = re[t];
            for (int i = e1; i < pe; ++i) {   // pad: own row, alpha 0
                eS[i] = n; eA0[i] = 0u; eA1[i] = 0u;
            }
        }
    }
    __syncthreads();

    // ---- aggregation ----
    const int q    = l >> 4;        // edge quarter 0..3
    const int m16  = l & 15;        // 16B group within the 256B row
    const int hsel = m16 >> 3;      // head pair (hsel, 2+hsel)
    const unsigned* eAh = hsel ? eA1 : eA0;

    for (int ln = wave; ln < 64; ln += 8) {
        int n = (b << 6) + ln;
        if (n >= N) break;
        const int start = rs[ln], end = re[ln];
        float a0 = 0.f, a1 = 0.f, a2 = 0.f, a3 = 0.f;
        float a4 = 0.f, a5 = 0.f, a6 = 0.f, a7 = 0.f;
        float dLo = 0.f, dHi = 0.f;

        for (int i = start; i < end; i += 24) {
            const int rem = min(end - i, 24);    // 8,16,24 (wave-uniform)
            int sk[6]; unsigned d[6]; uint4 u[6];
            #pragma unroll
            for (int k = 0; k < 6; ++k) if (4 * k < rem) {
                int j = i + 4 * k + q;
                sk[k] = eS[j]; d[k] = eAh[j];
            }
            #pragma unroll
            for (int k = 0; k < 6; ++k) if (4 * k < rem)
                u[k] = *(const uint4*)(h2 + (size_t)sk[k] * 64 + m16 * 4);
            #pragma unroll
            for (int k = 0; k < 6; ++k) if (4 * k < rem) {
                float wl = bf_lo(d[k]), wh = bf_hi(d[k]);
                dLo += wl; dHi += wh;
                a0 += wl * bf_lo(u[k].x); a4 += wh * bf_hi(u[k].x);
                a1 += wl * bf_lo(u[k].y); a5 += wh * bf_hi(u[k].y);
                a2 += wl * bf_lo(u[k].z); a6 += wh * bf_hi(u[k].z);
                a3 += wl * bf_lo(u[k].w); a7 += wh * bf_hi(u[k].w);
            }
        }

        // reduce across the 4 edge-quarters
        #pragma unroll
        for (int s = 16; s < 64; s <<= 1) {
            a0 += __shfl_xor(a0, s); a1 += __shfl_xor(a1, s);
            a2 += __shfl_xor(a2, s); a3 += __shfl_xor(a3, s);
            a4 += __shfl_xor(a4, s); a5 += __shfl_xor(a5, s);
            a6 += __shfl_xor(a6, s); a7 += __shfl_xor(a7, s);
            dLo += __shfl_xor(dLo, s); dHi += __shfl_xor(dHi, s);
        }

        // self-loop (fp32 exp, unnormalized), then normalize
        {
            float sLo = LEXP(a_src[(size_t)n * 4 + hsel]     + adl[ln][hsel]);
            float sHi = LEXP(a_src[(size_t)n * 4 + 2 + hsel] + adl[ln][2 + hsel]);
            uint4 u = *(const uint4*)(h2 + (size_t)n * 64 + m16 * 4);
            a0 += sLo * bf_lo(u.x); a4 += sHi * bf_hi(u.x);
            a1 += sLo * bf_lo(u.y); a5 += sHi * bf_hi(u.y);
            a2 += sLo * bf_lo(u.z); a6 += sHi * bf_hi(u.z);
            a3 += sLo * bf_lo(u.w); a7 += sHi * bf_hi(u.w);
            dLo += sLo; dHi += sHi;
        }
        const float ivLo = 1.f / dLo, ivHi = 1.f / dHi;

        // epilogue: channels 4*m16+{0..3} (lo) and +64 (hi)
        const int cb = 4 * m16;
        float p0 = 0.f, p1 = 0.f;
        float av0[4] = {a0, a1, a2, a3};
        float av1[4] = {a4, a5, a6, a7};
        #pragma unroll
        for (int c4 = 0; c4 < 4; ++c4) {
            int cLo = cb + c4, cHi = 64 + cb + c4;
            float rLo = fmaxf(av0[c4] * ivLo + b_gat[cLo], 0.f);
            float rHi = fmaxf(av1[c4] * ivHi + b_gat[cHi], 0.f);
            p0 += rLo * W_lin[cLo] + rHi * W_lin[cHi];
            p1 += rLo * W_lin[128 + cLo] + rHi * W_lin[128 + cHi];
        }
        #pragma unroll
        for (int s = 1; s < 16; s <<= 1) {
            p0 += __shfl_xor(p0, s);
            p1 += __shfl_xor(p1, s);
        }
        if (l == 0) {
            out[(size_t)n * 2]     = p0 + b_lin[0];
            out[(size_t)n * 2 + 1] = p1 + b_lin[1];
        }
    }
}

// ---------------- launch ----------------
extern "C" void kernel_launch(void* const* d_in, const int* in_sizes, int n_in,
                              void* d_out, int out_size, void* d_ws, size_t ws_size,
                              hipStream_t stream)
{
    const float* x       = (const float*)d_in[0];
    const int*   ei      = (const int*)d_in[1];
    const float* Wg      = (const float*)d_in[2];
    const float* att_src = (const float*)d_in[3];
    const float* att_dst = (const float*)d_in[4];
    const float* b_gat   = (const float*)d_in[5];
    const float* W_lin   = (const float*)d_in[6];
    const float* b_lin   = (const float*)d_in[7];
    float* out = (float*)d_out;

    const int N = in_sizes[0] / 128;
    const int E = in_sizes[1] / 2;
    const int NBKT = (N + 63) >> 6;            // buckets of 64 nodes (<=1600)
    const int CAP  = 1728;                     // max bucket (~1280) + pad (<=448)
    const int NBLKB = 256;
    const int CHUNK = (E + NBLKB - 1) / NBLKB; // <= 6272 (LDS dst cache)

    // workspace layout
    char* ws = (char*)d_ws;
    unsigned* h2  = (unsigned*)ws;                    // N*64 packed bf16x2
    float* a_src  = (float*)(h2 + (size_t)N * 64);    // N*4
    float* a_dst  = a_src + (size_t)N * 4;            // N*4
    unsigned* stage = (unsigned*)(a_dst + (size_t)N * 4); // NBKT*CAP (padded)
    int*   gcur   = (int*)(stage + (size_t)NBKT * CAP);   // NBKT

    k_gemm_init<<<513, 256, 0, stream>>>(
        x, Wg, att_src, att_dst, h2, a_src, a_dst, N, gcur, NBKT, CAP);
    k_partB2<<<NBLKB, 256, 0, stream>>>(ei, gcur, stage, E, NBKT, CHUNK);
    k_aggC<<<NBKT, 512, 0, stream>>>(stage, gcur, a_src, a_dst, h2,
                                     b_gat, W_lin, b_lin, out, N, CAP);
}

// Round 23
// 135.168 us; speedup vs baseline: 1.3037x; 1.3037x over previous
//
#include <hip/hip_runtime.h>

#define NSLOPE  0.2f
#define LEXP(v) __expf((v) >= 0.f ? (v) : NSLOPE * (v))

typedef __attribute__((ext_vector_type(8))) short bf16x8;
typedef __attribute__((ext_vector_type(4))) float f32x4;

__device__ __forceinline__ unsigned bf16_rne(float f) {
    unsigned x = __float_as_uint(f);
    return (x + 0x7fffu + ((x >> 16) & 1u)) >> 16;
}
__device__ __forceinline__ float bf_lo(unsigned u) { return __uint_as_float(u << 16); }
__device__ __forceinline__ float bf_hi(unsigned u) { return __uint_as_float(u & 0xffff0000u); }

// ---- Kernel 1: blocks [0,512): h2 = bf16(x@W^T) via MFMA + att dots via
// 4 extra MFMAs against watt = att@W. Block 512: init gcur[b] = b*CAP.
__global__ __launch_bounds__(256) void k_gemm_init(
    const float* __restrict__ x, const float* __restrict__ Wg,
    const float* __restrict__ att_src, const float* __restrict__ att_dst,
    unsigned* __restrict__ h2, float* __restrict__ a_src, float* __restrict__ a_dst,
    int N, int* __restrict__ gcur, int nbkt, int cap)
{
    __shared__ unsigned short Wl[128 * 136];   // bf16 W (34.8KB)
    __shared__ unsigned short wattH[8][128];   // bf16 watt (2KB)

    const int t = threadIdx.x;

    if (blockIdx.x >= 512) {                   // ---- gcur init role ----
        for (int i = t; i < nbkt; i += 256) gcur[i] = i * cap;
        return;
    }

    // ---- GEMM role ----
    for (int i = t; i < 128 * 32; i += 256) {
        int r = i >> 5, c4 = (i & 31) * 4;
        float4 w = *(const float4*)(Wg + r * 128 + c4);
        unsigned* wp = (unsigned*)((char*)Wl + r * 272 + c4 * 2);
        wp[0] = bf16_rne(w.x) | (bf16_rne(w.y) << 16);
        wp[1] = bf16_rne(w.z) | (bf16_rne(w.w) << 16);
    }
    // watt[j][f]: j<4 -> src head j; j>=4 -> dst head j-4
    for (int idx = t; idx < 1024; idx += 256) {
        int j = idx >> 7, f = idx & 127;
        const float* av = (j < 4) ? (att_src + j * 32) : (att_dst + (j - 4) * 32);
        int hh = (j & 3) * 32;
        float s = 0.f;
        #pragma unroll 8
        for (int k = 0; k < 32; ++k)
            s += av[k] * Wg[(size_t)(hh + k) * 128 + f];
        wattH[j][f] = (unsigned short)bf16_rne(s);
    }
    __syncthreads();

    const int wave = t >> 6, l = t & 63;
    const int col = l & 15, kg = l >> 4;

    union { bf16x8 v; unsigned short s[8]; } batt[4];
    #pragma unroll
    for (int s4 = 0; s4 < 4; ++s4) {
        #pragma unroll
        for (int jj = 0; jj < 8; ++jj)
            batt[s4].s[jj] = (col < 8) ? wattH[col][s4 * 32 + kg * 8 + jj]
                                       : (unsigned short)0;
    }

    const int nwaves = 512 * 4;
    const int wid = blockIdx.x * 4 + wave;

    for (int mb = wid * 16; mb < N; mb += nwaves * 16) {
        union { bf16x8 v; unsigned u[4]; } af[4];
        int row = mb + col; if (row >= N) row = N - 1;
        const float* xr = x + (size_t)row * 128 + kg * 8;
        #pragma unroll
        for (int s = 0; s < 4; ++s) {
            float4 xa = *(const float4*)(xr + s * 32);
            float4 xb = *(const float4*)(xr + s * 32 + 4);
            af[s].u[0] = bf16_rne(xa.x) | (bf16_rne(xa.y) << 16);
            af[s].u[1] = bf16_rne(xa.z) | (bf16_rne(xa.w) << 16);
            af[s].u[2] = bf16_rne(xb.x) | (bf16_rne(xb.y) << 16);
            af[s].u[3] = bf16_rne(xb.z) | (bf16_rne(xb.w) << 16);
        }

        f32x4 acc[8];
        #pragma unroll
        for (int tl = 0; tl < 8; ++tl) acc[tl] = (f32x4){0.f, 0.f, 0.f, 0.f};
        f32x4 accd = (f32x4){0.f, 0.f, 0.f, 0.f};

        #pragma unroll
        for (int s = 0; s < 4; ++s) {
            #pragma unroll
            for (int tl = 0; tl < 8; ++tl) {
                const bf16x8 bf = *(const bf16x8*)((char*)Wl
                    + (tl * 16 + col) * 272 + (s * 32 + kg * 8) * 2);
                acc[tl] = __builtin_amdgcn_mfma_f32_16x16x32_bf16(af[s].v, bf, acc[tl], 0, 0, 0);
            }
            accd = __builtin_amdgcn_mfma_f32_16x16x32_bf16(af[s].v, batt[s].v, accd, 0, 0, 0);
        }

        #pragma unroll
        for (int tl = 0; tl < 4; ++tl) {
            #pragma unroll
            for (int r = 0; r < 4; ++r) {
                int node = mb + kg * 4 + r;
                if (node < N) {
                    unsigned w = bf16_rne(acc[tl][r]) | (bf16_rne(acc[tl + 4][r]) << 16);
                    h2[(size_t)node * 64 + tl * 16 + col] = w;
                }
            }
        }
        if (col < 8) {
            float* bp = (col < 4) ? a_src : a_dst;
            const int j = col & 3;
            #pragma unroll
            for (int r = 0; r < 4; ++r) {
                int node = mb + kg * 4 + r;
                if (node < N) bp[(size_t)node * 4 + j] = accd[r];
            }
        }
    }
}

// ---- Kernel 2: fused count + reserve + scatter into padded bucket regions.
// Buckets of 64 nodes: bucket = d>>6, dlow = d&63 packed at bit 26.
__global__ __launch_bounds__(256) void k_partB2(
    const int* __restrict__ ei, int* __restrict__ gcur,
    unsigned* __restrict__ stage, int E, int nbkt, int chunk)
{
    __shared__ int dstc[6272];
    __shared__ int lcnt[1600];
    __shared__ int lbase[1600];
    const int t = threadIdx.x;
    for (int i = t; i < nbkt; i += 256) lcnt[i] = 0;
    __syncthreads();
    const int lo = blockIdx.x * chunk, hi = min(lo + chunk, E);
    for (int e = lo + t; e < hi; e += 256) {
        int d = ei[E + e];
        dstc[e - lo] = d;
        atomicAdd(&lcnt[d >> 6], 1);
    }
    __syncthreads();
    for (int i = t; i < nbkt; i += 256) {
        int c = lcnt[i];
        lbase[i] = (c > 0) ? atomicAdd(&gcur[i], c) : 0;
    }
    __syncthreads();
    for (int e = lo + t; e < hi; e += 256) {
        int s = ei[e];
        int d = dstc[e - lo];
        int pos = atomicAdd(&lbase[d >> 6], 1);
        stage[pos] = (unsigned)s | ((unsigned)(d & 63) << 26);
    }
}

// ---- Kernel 3 (fused partC + agg), 512 threads / 8 waves per block.
// Phases: count, scan, scatter edges into LDS (bf16 exps from L2-resident
// a_src gathers), pad runs to multiples of 8. Aggregation with inline
// denominator: edge metadata from LDS, h2 gathers from global, fp32
// self-exp in-register, normalize at end, fused classifier.
__global__ __launch_bounds__(512) void k_aggC(
    const unsigned* __restrict__ stage, const int* __restrict__ gcur,
    const float* __restrict__ a_src, const float* __restrict__ a_dst,
    const unsigned* __restrict__ h2, const float* __restrict__ b_gat,
    const float* __restrict__ W_lin, const float* __restrict__ b_lin,
    float* __restrict__ out, int N, int cap)
{
    __shared__ int      eS[1728];
    __shared__ unsigned eA0[1728];
    __shared__ unsigned eA1[1728];
    __shared__ int cnt[64];
    __shared__ int cur[64];
    __shared__ int rs[64];
    __shared__ int re[64];
    __shared__ float adl[64][4];

    const int b = blockIdx.x, t = threadIdx.x;
    const int wave = t >> 6, l = t & 63;

    if (t < 64) {
        cnt[t] = 0;
        int n = (b << 6) + t;
        float4 v = (n < N) ? *(const float4*)(a_dst + (size_t)n * 4)
                           : make_float4(0.f, 0.f, 0.f, 0.f);
        *(float4*)adl[t] = v;
    }
    __syncthreads();
    const int slo = b * cap;
    const int ecnt = gcur[b] - slo;
    for (int e = t; e < ecnt; e += 512)
        atomicAdd(&cnt[stage[slo + e] >> 26], 1);
    __syncthreads();
    if (t < 64) {                   // single-wave scan (wave 0)
        int v = cnt[t];
        int pv = (v + 7) & ~7;      // padded run length
        int sc = pv;
        #pragma unroll
        for (int m = 1; m < 64; m <<= 1) {
            int u = __shfl_up(sc, m);
            if (t >= m) sc += u;
        }
        int c0 = sc - pv;           // LDS-local offset
        cur[t] = c0;
        rs[t] = c0; re[t] = c0 + pv;
    }
    __syncthreads();
    for (int e = t; e < ecnt; e += 512) {
        unsigned u = stage[slo + e];
        int s  = (int)(u & 0x3FFFFFFu);
        int dl = (int)(u >> 26);
        float4 av = *(const float4*)(a_src + (size_t)s * 4);
        float x0 = LEXP(av.x + adl[dl][0]);
        float x1 = LEXP(av.y + adl[dl][1]);
        float x2 = LEXP(av.z + adl[dl][2]);
        float x3 = LEXP(av.w + adl[dl][3]);
        int pos = atomicAdd(&cur[dl], 1);
        eS[pos]  = s;
        eA0[pos] = bf16_rne(x0) | (bf16_rne(x2) << 16);
        eA1[pos] = bf16_rne(x1) | (bf16_rne(x3) << 16);
    }
    __syncthreads();
    if (t < 64) {
        int n = (b << 6) + t;
        if (n < N) {
            const int e1 = cur[t], pe = re[t];
            for (int i = e1; i < pe; ++i) {   // pad: own row, alpha 0
                eS[i] = n; eA0[i] = 0u; eA1[i] = 0u;
            }
        }
    }
    __syncthreads();

    // ---- aggregation: wave w handles local nodes w, w+8, ... ----
    const int m    = l & 31;
    const int half = l >> 5;
    const int cch  = 2 * m;
    const int hsel = m >> 4;
    const unsigned* eAh = hsel ? eA1 : eA0;

    for (int ln = wave; ln < 64; ln += 8) {
        int n = (b << 6) + ln;
        if (n >= N) break;
        const int start = rs[ln], end = re[ln];
        float a00 = 0.f, a01 = 0.f, a10 = 0.f, a11 = 0.f;
        float dA = 0.f, dB = 0.f;

        int i = start;
        for (; i + 16 <= end; i += 16) {
            int sk[8]; unsigned d[8]; uint2 u[8];
            #pragma unroll
            for (int k = 0; k < 8; ++k) {
                int j = i + 2 * k + half;
                sk[k] = eS[j];
                d[k]  = eAh[j];
            }
            #pragma unroll
            for (int k = 0; k < 8; ++k)
                u[k] = *(const uint2*)(h2 + (size_t)sk[k] * 64 + cch);
            #pragma unroll
            for (int k = 0; k < 8; ++k) {
                float wl = bf_lo(d[k]), wh = bf_hi(d[k]);
                dA += wl; dB += wh;
                a00 += wl * bf_lo(u[k].x); a01 += wh * bf_hi(u[k].x);
                a10 += wl * bf_lo(u[k].y); a11 += wh * bf_hi(u[k].y);
            }
        }
        if (i < end) {               // exactly 8 remaining (padded)
            int sk[4]; unsigned d[4]; uint2 u[4];
            #pragma unroll
            for (int k = 0; k < 4; ++k) {
                int j = i + 2 * k + half;
                sk[k] = eS[j];
                d[k]  = eAh[j];
            }
            #pragma unroll
            for (int k = 0; k < 4; ++k)
                u[k] = *(const uint2*)(h2 + (size_t)sk[k] * 64 + cch);
            #pragma unroll
            for (int k = 0; k < 4; ++k) {
                float wl = bf_lo(d[k]), wh = bf_hi(d[k]);
                dA += wl; dB += wh;
                a00 += wl * bf_lo(u[k].x); a01 += wh * bf_hi(u[k].x);
                a10 += wl * bf_lo(u[k].y); a11 += wh * bf_hi(u[k].y);
            }
        }

        a00 += __shfl_xor(a00, 32);
        a01 += __shfl_xor(a01, 32);
        a10 += __shfl_xor(a10, 32);
        a11 += __shfl_xor(a11, 32);
        dA  += __shfl_xor(dA, 32);
        dB  += __shfl_xor(dB, 32);

        // self-loop (fp32 exp, unnormalized), then normalize
        {
            float sA = LEXP(a_src[(size_t)n * 4 + hsel]     + adl[ln][hsel]);
            float sB = LEXP(a_src[(size_t)n * 4 + 2 + hsel] + adl[ln][2 + hsel]);
            uint2 u = *(const uint2*)(h2 + (size_t)n * 64 + cch);
            a00 += sA * bf_lo(u.x); a01 += sB * bf_hi(u.x);
            a10 += sA * bf_lo(u.y); a11 += sB * bf_hi(u.y);
            dA += sA; dB += sB;
        }
        const float ivA = 1.f / dA, ivB = 1.f / dB;
        a00 *= ivA; a01 *= ivB; a10 *= ivA; a11 *= ivB;

        float r0 = fmaxf(a00 + b_gat[cch],      0.f);
        float r1 = fmaxf(a01 + b_gat[cch + 64], 0.f);
        float r2 = fmaxf(a10 + b_gat[cch + 1],  0.f);
        float r3 = fmaxf(a11 + b_gat[cch + 65], 0.f);
        float p0 = r0 * W_lin[cch]       + r1 * W_lin[cch + 64]
                 + r2 * W_lin[cch + 1]   + r3 * W_lin[cch + 65];
        float p1 = r0 * W_lin[128 + cch]     + r1 * W_lin[128 + cch + 64]
                 + r2 * W_lin[128 + cch + 1] + r3 * W_lin[128 + cch + 65];
        #pragma unroll
        for (int s = 1; s < 32; s <<= 1) {
            p0 += __shfl_xor(p0, s);
            p1 += __shfl_xor(p1, s);
        }
        if (l == 0) {
            out[(size_t)n * 2]     = p0 + b_lin[0];
            out[(size_t)n * 2 + 1] = p1 + b_lin[1];
        }
    }
}

// ---------------- launch ----------------
extern "C" void kernel_launch(void* const* d_in, const int* in_sizes, int n_in,
                              void* d_out, int out_size, void* d_ws, size_t ws_size,
                              hipStream_t stream)
{
    const float* x       = (const float*)d_in[0];
    const int*   ei      = (const int*)d_in[1];
    const float* Wg      = (const float*)d_in[2];
    const float* att_src = (const float*)d_in[3];
    const float* att_dst = (const float*)d_in[4];
    const float* b_gat   = (const float*)d_in[5];
    const float* W_lin   = (const float*)d_in[6];
    const float* b_lin   = (const float*)d_in[7];
    float* out = (float*)d_out;

    const int N = in_sizes[0] / 128;
    const int E = in_sizes[1] / 2;
    const int NBKT = (N + 63) >> 6;            // buckets of 64 nodes (<=1600)
    const int CAP  = 1728;                     // max bucket (~1280) + pad (<=448)
    const int NBLKB = 256;
    const int CHUNK = (E + NBLKB - 1) / NBLKB; // <= 6272 (LDS dst cache)

    // workspace layout
    char* ws = (char*)d_ws;
    unsigned* h2  = (unsigned*)ws;                    // N*64 packed bf16x2
    float* a_src  = (float*)(h2 + (size_t)N * 64);    // N*4
    float* a_dst  = a_src + (size_t)N * 4;            // N*4
    unsigned* stage = (unsigned*)(a_dst + (size_t)N * 4); // NBKT*CAP (padded)
    int*   gcur   = (int*)(stage + (size_t)NBKT * CAP);   // NBKT

    k_gemm_init<<<513, 256, 0, stream>>>(
        x, Wg, att_src, att_dst, h2, a_src, a_dst, N, gcur, NBKT, CAP);
    k_partB2<<<NBLKB, 256, 0, stream>>>(ei, gcur, stage, E, NBKT, CHUNK);
    k_aggC<<<NBKT, 512, 0, stream>>>(stage, gcur, a_src, a_dst, h2,
                                     b_gat, W_lin, b_lin, out, N, CAP);
}